// Round 8
// baseline (154.802 us; speedup 1.0000x reference)
//
#include <hip/hip_runtime.h>
#include <hip/hip_bf16.h>
#include <cstdint>
#include <cmath>

// Problem constants — inputs/outputs are fp32.
// LEDGER: R0 152.3 | R1 167.4 | R2 151.8 | R3 150.2 | R4 152.3 | R5 172.9 |
//         R6 153.3 | R7 148.8 (best: interleaved float4 agg store).
// LESSON (R7): row-major LDS = 16-way conflict; XOR slot swizzle -> 0 (verified).
// LESSON (R8): __syncthreads() drains vmcnt(0)/K-step; raw s_barrier + counted
// vmcnt in K-loops.
// LESSON (R10/R11): rocprof per-kernel dur unreliable under replay; trust
// bench totals only.
// LESSON (R12): reg-staging COMMIT (ds_write+lgkmcnt per phase) regressed —
// but DMA staging of fp32 with convert-at-fragment-read avoids that path.
// LESSON (R13): p3+out fusion lost (1 blk/CU serial scan uncovered); keep split.
// LESSON (R14 = R7): write-allocate on scattered 8B stores is real (~1.4us);
// interleave+float4 fixed it.
// R8: delete the xs convert round-trip. gemm_zh stages A as FP32 via
// global_load_lds (pre-swizzled source, linear LDS, 3-buffer half-step
// rotation, counted vmcnt(6)) and converts fp32->bf16 at fragment-read time
// (RNE packs == f2bf bits -> absmax unchanged). k_convert shrinks to W-only.
// Net HBM ~ -28MB and convert kernel -7us. Pre-commit: >=149 -> revert R7.
#define T_SEQ 16384
#define DMODEL 512
#define NCHUNK 512        // scan chunks (= T_SEQ/LCHUNK)
#define LCHUNK 32
#define W_N    (DMODEL * DMODEL)
#define N4_W   (W_N / 4)
#define N4_W3  (3 * N4_W)
#define NTILE  8          // K tiles of 64 (gemm_out)
#define NHS    16         // K half-steps of 32 (gemm_zh)

typedef __bf16 bf16x8 __attribute__((ext_vector_type(8)));
typedef float  f32x4  __attribute__((ext_vector_type(4)));

using bf16 = __hip_bfloat16;

__device__ __forceinline__ void load_lds16(const void* g, void* l) {
    __builtin_amdgcn_global_load_lds((const __attribute__((address_space(1))) void*)g,
                                     (__attribute__((address_space(3))) void*)l,
                                     16, 0, 0);
}

__device__ __forceinline__ unsigned short f2bf(float f) {
    union { float f; unsigned u; } v; v.f = f;
    const unsigned r = (v.u + 0x7FFFu + ((v.u >> 16) & 1u)) >> 16;
    return (unsigned short)r;
}
__device__ __forceinline__ float bf2f(unsigned short u) {
    union { unsigned u; float f; } v; v.u = ((unsigned)u) << 16;
    return v.f;
}

// 8 fp32 -> bf16x8 fragment, RNE (bit-identical to f2bf)
__device__ __forceinline__ bf16x8 packfrag(const f32x4 lo, const f32x4 hi) {
    __hip_bfloat162 p0 = __float22bfloat162_rn(make_float2(lo[0], lo[1]));
    __hip_bfloat162 p1 = __float22bfloat162_rn(make_float2(lo[2], lo[3]));
    __hip_bfloat162 p2 = __float22bfloat162_rn(make_float2(hi[0], hi[1]));
    __hip_bfloat162 p3 = __float22bfloat162_rn(make_float2(hi[2], hi[3]));
    union { unsigned u[4]; bf16x8 v; } r;
    r.u[0] = *(const unsigned*)&p0; r.u[1] = *(const unsigned*)&p1;
    r.u[2] = *(const unsigned*)&p2; r.u[3] = *(const unsigned*)&p3;
    return r.v;
}

// ordered pair-combine: first=(fA,fB) then second=(sA,sB)
__device__ __forceinline__ void comb(float& A, float& B, float fA, float fB,
                                     float sA, float sB) {
    A = fA * sA;
    B = sA * fB + sB;
}

// ---------------------------------------------------------------------------
// Kernel 0: convert Wz, Wh, Wo fp32 -> bf16 (W only now, ~4.5 MB, ~1 us).
// ---------------------------------------------------------------------------
__global__ __launch_bounds__(256) void k_convert(
    const float* __restrict__ Wz, const float* __restrict__ Wh,
    const float* __restrict__ Wo,
    bf16* __restrict__ Wz_c, bf16* __restrict__ Wh_c, bf16* __restrict__ Wo_c)
{
    const int i = blockIdx.x * 256 + threadIdx.x;
    if (i >= N4_W3) return;
    const int w = i >> 16;
    const int o = i & 65535;
    const float* src = (w == 0) ? Wz : (w == 1) ? Wh : Wo;
    bf16* dst = (w == 0) ? Wz_c : (w == 1) ? Wh_c : Wo_c;
    const float4 v = ((const float4*)src)[o];
    ushort4 r;
    r.x = f2bf(v.x); r.y = f2bf(v.y); r.z = f2bf(v.z); r.w = f2bf(v.w);
    ((ushort4*)dst)[o] = r;
}

// ---------------------------------------------------------------------------
// Kernel 1: fused dual GEMM + scan phase 1 — fp32-A-direct.
// Tile 256x128, 512 thr / 8 waves. A staged as FP32 via DMA (32 KB/half);
// Z/H staged bf16 (8 KB/half each). 3-buffer half-step rotation (144 KB LDS,
// 1 blk/CU — bench-fine per R3). Counted vmcnt(6): stage s+2 issued at phase
// s; wait leaves next stage in flight. fp32->bf16 conversion at fragment
// read (2x ds_read_b128 + 4 RNE packs per A-fragment; identical bits to the
// old pre-convert). XOR swizzles: A 3-bit key (8 slots/128B row), Z/H 2-bit
// key (4 slots/64B row) — both verified-conflict-free family.
// ---------------------------------------------------------------------------
__global__ __launch_bounds__(512) void gemm_zh(
    const float* __restrict__ xs, const bf16* __restrict__ Wz, const float* __restrict__ bz,
    const bf16* __restrict__ Wh, const float* __restrict__ bh,
    unsigned int* __restrict__ ab_ws,
    float* __restrict__ ABagg)
{
    __shared__ float  Af[3][256 * 32];   // 96 KB
    __shared__ __bf16 Zs[3][128 * 32];   // 24 KB
    __shared__ __bf16 Hs[3][128 * 32];   // 24 KB

    const int tid  = threadIdx.x;
    const int bm   = blockIdx.x;   // 0..63  (M tile of 256)
    const int bn   = blockIdx.y;   // 0..3   (N tile of 128)
    const int lane = tid & 63;
    const int wave = tid >> 6;     // 0..7
    const int wm   = wave >> 1;    // 0..3
    const int wn   = wave & 1;     // 0..1
    const int quad = lane >> 4;
    const int col  = lane & 15;

    f32x4 accz[4][4], acch[4][4];
    #pragma unroll
    for (int i = 0; i < 4; ++i)
        #pragma unroll
        for (int j = 0; j < 4; ++j) {
            accz[i][j] = (f32x4){0.f, 0.f, 0.f, 0.f};
            acch[i][j] = (f32x4){0.f, 0.f, 0.f, 0.f};
        }

    // A staging: cell = it*512 + tid (16B cells); row = it*64 + (tid>>3);
    // phys slot (tid&7) of row holds logical slot (tid&7)^(row&7)  ->
    // pre-swizzled source column.
    const int arow0 = tid >> 3;                          // +64 per it
    const int aslot = (tid & 7) ^ ((tid >> 3) & 7);      // constant per thread
    const float* ag = xs + (size_t)(bm * 256 + arow0) * DMODEL + aslot * 4;

    // W staging: row = tid>>2, 16B slot (tid&3), key (row>>1)&3 (R7-verified)
    const int wrow = tid >> 2;
    const int wq   = (tid & 3) ^ ((tid >> 3) & 3);
    const bf16* zg = Wz + (size_t)(bn * 128 + wrow) * DMODEL + wq * 8;
    const bf16* hg = Wh + (size_t)(bn * 128 + wrow) * DMODEL + wq * 8;

    // A fragment read offsets: row r = wm*64+i*16+col, key = r&7 = col&7;
    // logical fp32 slots {2*quad, 2*quad+1} -> phys = logical ^ key.
    const int akey = col & 7;
    int aoffL[4], aoffH[4];
    #pragma unroll
    for (int i = 0; i < 4; ++i) {
        const int base = (wm * 64 + i * 16 + col) * 32;
        aoffL[i] = base + ((2 * quad)     ^ akey) * 4;
        aoffH[i] = base + ((2 * quad + 1) ^ akey) * 4;
    }
    // Z/H fragment read offsets (bf16, R7-verified swizzle)
    const int fq = quad ^ ((col >> 1) & 3);
    int offB[4];
    #pragma unroll
    for (int j = 0; j < 4; ++j)
        offB[j] = (wn * 64 + j * 16 + col) * 32 + fq * 8;

    // one half-step stage = 4 A-DMA + 1 Z-DMA + 1 H-DMA = 6 vm-ops/thread
    auto STAGE = [&](int s, int p) {
        const int k0 = s * 32;
        #pragma unroll
        for (int it = 0; it < 4; ++it)
            load_lds16(ag + (size_t)(it * 64) * DMODEL + k0,
                       &Af[p][(it * 512 + tid) * 4]);
        load_lds16(zg + k0, &Zs[p][tid * 8]);
        load_lds16(hg + k0, &Hs[p][tid * 8]);
    };

    // prologue: two half-steps in flight
    STAGE(0, 0); STAGE(1, 1);

    #pragma unroll
    for (int s = 0; s < NHS; ++s) {
        const int p = s % 3;
        if (s + 1 < NHS) {
            asm volatile("s_waitcnt vmcnt(6)" ::: "memory");   // half s landed
        } else {
            asm volatile("s_waitcnt vmcnt(0)" ::: "memory");
        }
        __builtin_amdgcn_s_barrier();
        __builtin_amdgcn_sched_barrier(0);
        if (s + 2 < NHS) STAGE(s + 2, (s + 2) % 3);   // buffer (s-1)%3: readers done

        bf16x8 af[4], zf[4], hf[4];
        #pragma unroll
        for (int i = 0; i < 4; ++i) {
            const f32x4 lo = *(const f32x4*)&Af[p][aoffL[i]];
            const f32x4 hi = *(const f32x4*)&Af[p][aoffH[i]];
            af[i] = packfrag(lo, hi);
        }
        #pragma unroll
        for (int j = 0; j < 4; ++j)
            zf[j] = *(const bf16x8*)&Zs[p][offB[j]];
        __builtin_amdgcn_s_setprio(1);
        #pragma unroll
        for (int i = 0; i < 4; ++i)
            #pragma unroll
            for (int j = 0; j < 4; ++j)
                accz[i][j] = __builtin_amdgcn_mfma_f32_16x16x32_bf16(af[i], zf[j], accz[i][j], 0, 0, 0);
        __builtin_amdgcn_s_setprio(0);

        #pragma unroll
        for (int j = 0; j < 4; ++j)
            hf[j] = *(const bf16x8*)&Hs[p][offB[j]];
        __builtin_amdgcn_s_setprio(1);
        #pragma unroll
        for (int i = 0; i < 4; ++i)
            #pragma unroll
            for (int j = 0; j < 4; ++j)
                acch[i][j] = __builtin_amdgcn_mfma_f32_16x16x32_bf16(af[i], hf[j], acch[i][j], 0, 0, 0);
        __builtin_amdgcn_s_setprio(0);
    }

    // epilogue: D layout col=lane&15 (n), row=quad*4+reg (m) — R7-verbatim
    const int c_lo = bm * 8 + wm * 2;      // 8 chunks per 256-row tile
    #pragma unroll
    for (int j = 0; j < 4; ++j) {
        const int n = bn * 128 + wn * 64 + j * 16 + col;
        const float bzv = bz[n];
        const float bhv = bh[n];
        float cA[4], cB[4];
        #pragma unroll
        for (int i = 0; i < 4; ++i) {
            const int mbase = bm * 256 + wm * 64 + i * 16 + quad * 4;
            float A = 1.f, B = 0.f;
            #pragma unroll
            for (int r = 0; r < 4; ++r) {
                const float zpre = accz[i][j][r] + bzv;
                const float hpre = acch[i][j][r] + bhv;
                const float z = 1.f / (1.f + __expf(-zpre));
                const float a = 1.f - z;
                const float b = z * hpre;
                const size_t idx = (size_t)(mbase + r) * DMODEL + n;
                ab_ws[idx] = (unsigned)f2bf(a) | ((unsigned)f2bf(b) << 16);
                A = a * A;
                B = a * B + b;
            }
            cA[i] = A; cB[i] = B;
        }
        #pragma unroll
        for (int i = 0; i < 4; ++i) {
            float pA = __shfl_xor(cA[i], 16);
            float pB = __shfl_xor(cB[i], 16);
            const bool hi1 = quad & 1;
            comb(cA[i], cB[i], hi1 ? pA : cA[i], hi1 ? pB : cB[i],
                               hi1 ? cA[i] : pA, hi1 ? cB[i] : pB);
            pA = __shfl_xor(cA[i], 32);
            pB = __shfl_xor(cB[i], 32);
            const bool hi2 = quad >> 1;
            comb(cA[i], cB[i], hi2 ? pA : cA[i], hi2 ? pB : cB[i],
                               hi2 ? cA[i] : pA, hi2 ? cB[i] : pB);
        }
        float Alo, Blo, Ahi, Bhi;
        comb(Alo, Blo, cA[0], cB[0], cA[1], cB[1]);
        comb(Ahi, Bhi, cA[2], cB[2], cA[3], cB[3]);
        if (quad == 0) {   // interleaved {A,B} pairs: one 16B store per lane
            *(float4*)&ABagg[((size_t)n * NCHUNK + c_lo) * 2] =
                make_float4(Alo, Blo, Ahi, Bhi);
        }
    }
}

// ---------------------------------------------------------------------------
// Kernel 2: per-channel Hillis-Steele over NCHUNK chunk aggregates.
// Reads interleaved ABagg as coalesced float2.
// ---------------------------------------------------------------------------
__global__ __launch_bounds__(512) void scan_p2(
    const float* __restrict__ ABagg, float* __restrict__ HpreT)
{
    const int h = blockIdx.x;
    const int c = threadIdx.x;
    __shared__ float sA[NCHUNK], sB[NCHUNK];

    const float2 v = ((const float2*)ABagg)[(size_t)h * NCHUNK + c];
    float A = v.x;
    float B = v.y;
    sA[c] = A; sB[c] = B;
    __syncthreads();

    for (int off = 1; off < NCHUNK; off <<= 1) {
        float pA = 1.f, pB = 0.f;
        if (c >= off) { pA = sA[c - off]; pB = sB[c - off]; }
        __syncthreads();
        const float nB = A * pB + B;   // uses old A
        const float nA = A * pA;
        A = nA; B = nB;
        sA[c] = A; sB[c] = B;
        __syncthreads();
    }
    const float hp = (c == 0) ? 0.f : sB[c - 1];
    HpreT[(size_t)h * NCHUNK + c] = hp;
}

// ---------------------------------------------------------------------------
// Kernel 3: replay chunk recurrence from HpreT; write bf16 states.
// 1 channel/thread, grid (512 chunks x 2 halves) x 256 threads -> 4 blk/CU.
// ---------------------------------------------------------------------------
__global__ __launch_bounds__(256) void scan_p3(
    const unsigned int* __restrict__ ab_ws, const float* __restrict__ HpreT,
    unsigned short* __restrict__ states)
{
    const int tid = threadIdx.x;
    const int c   = blockIdx.x;
    const int ch  = blockIdx.y * 256 + tid;
    float H = HpreT[(size_t)ch * NCHUNK + c];       // one-time gather
    const size_t base = (size_t)(c * LCHUNK) * DMODEL + ch;
    #pragma unroll 8
    for (int i = 0; i < LCHUNK; ++i) {
        const unsigned u = ab_ws[base + (size_t)i * DMODEL];
        const float a = bf2f((unsigned short)(u & 0xFFFFu));
        const float b = bf2f((unsigned short)(u >> 16));
        H = a * H + b;
        states[base + (size_t)i * DMODEL] = f2bf(H);
    }
}

// ---------------------------------------------------------------------------
// Kernel 4: out = states @ Wo^T + bo — R3/R7-proven 256x128 template.
// 512 thr / 8 waves, BK=64 as 2x32 halves, 96 KB LDS, counted vmcnt(3),
// setprio around MFMA clusters.
// ---------------------------------------------------------------------------
__global__ __launch_bounds__(512, 2) void gemm_out(
    const bf16* __restrict__ states, const bf16* __restrict__ Wo, const float* __restrict__ bo,
    float* __restrict__ out)
{
    __shared__ __bf16 As[2][2][256 * 32];   // 64 KB
    __shared__ __bf16 Bs[2][2][128 * 32];   // 32 KB

    const int tid  = threadIdx.x;
    const int bm   = blockIdx.x;   // 0..63
    const int bn   = blockIdx.y;   // 0..3
    const int lane = tid & 63;
    const int wave = tid >> 6;
    const int wm   = wave >> 1;    // 0..3
    const int wn   = wave & 1;     // 0..1
    const int quad = lane >> 4;
    const int col  = lane & 15;

    f32x4 acc[4][4];
    #pragma unroll
    for (int i = 0; i < 4; ++i)
        #pragma unroll
        for (int j = 0; j < 4; ++j)
            acc[i][j] = (f32x4){0.f, 0.f, 0.f, 0.f};

    const int srow = tid >> 2;
    const int wq   = (tid & 3) ^ ((tid >> 3) & 3);
    const bf16* ag = states + (size_t)(bm * 256 + srow) * DMODEL + wq * 8;
    const bf16* bg = Wo     + (size_t)(bn * 128 + srow) * DMODEL + wq * 8;

    const int fq = quad ^ ((col >> 1) & 3);
    int offA[4], offB[4];
    #pragma unroll
    for (int i = 0; i < 4; ++i) {
        offA[i] = (wm * 64 + i * 16 + col) * 32 + fq * 8;
        offB[i] = (wn * 64 + i * 16 + col) * 32 + fq * 8;
    }

    auto STAGE_HALF = [&](int t, int h) {
        const int b  = t & 1;
        const int ko = t * 64 + h * 32;
        load_lds16(ag + ko,                        &As[b][h][tid * 8]);
        load_lds16(ag + (size_t)128 * DMODEL + ko, &As[b][h][(512 + tid) * 8]);
        load_lds16(bg + ko,                        &Bs[b][h][tid * 8]);
    };

    STAGE_HALF(0, 0); STAGE_HALF(0, 1);

    #pragma unroll
    for (int t = 0; t < NTILE; ++t) {
        const int b = t & 1;
        bf16x8 af[4], bf[4];

        // ---- Phase 0: k-half 0 (fresh) ----
        asm volatile("s_waitcnt vmcnt(3)" ::: "memory");
        __builtin_amdgcn_s_barrier();
        __builtin_amdgcn_sched_barrier(0);
        if (t + 1 < NTILE) STAGE_HALF(t + 1, 0);
        #pragma unroll
        for (int i = 0; i < 4; ++i) {
            af[i] = *(const bf16x8*)&As[b][0][offA[i]];
            bf[i] = *(const bf16x8*)&Bs[b][0][offB[i]];
        }
        __builtin_amdgcn_s_setprio(1);
        #pragma unroll
        for (int i = 0; i < 4; ++i)
            #pragma unroll
            for (int j = 0; j < 4; ++j)
                acc[i][j] = __builtin_amdgcn_mfma_f32_16x16x32_bf16(af[i], bf[j], acc[i][j], 0, 0, 0);
        __builtin_amdgcn_s_setprio(0);

        // ---- Phase 1: k-half 1 (fresh) ----
        if (t + 1 < NTILE) {
            asm volatile("s_waitcnt vmcnt(3)" ::: "memory");
        } else {
            asm volatile("s_waitcnt vmcnt(0)" ::: "memory");
        }
        __builtin_amdgcn_s_barrier();
        __builtin_amdgcn_sched_barrier(0);
        if (t + 1 < NTILE) STAGE_HALF(t + 1, 1);
        #pragma unroll
        for (int i = 0; i < 4; ++i) {
            af[i] = *(const bf16x8*)&As[b][1][offA[i]];
            bf[i] = *(const bf16x8*)&Bs[b][1][offB[i]];
        }
        __builtin_amdgcn_s_setprio(1);
        #pragma unroll
        for (int i = 0; i < 4; ++i)
            #pragma unroll
            for (int j = 0; j < 4; ++j)
                acc[i][j] = __builtin_amdgcn_mfma_f32_16x16x32_bf16(af[i], bf[j], acc[i][j], 0, 0, 0);
        __builtin_amdgcn_s_setprio(0);
    }

    #pragma unroll
    for (int j = 0; j < 4; ++j) {
        const int n = bn * 128 + wn * 64 + j * 16 + col;
        const float bov = bo[n];
        #pragma unroll
        for (int i = 0; i < 4; ++i) {
            const int mbase = bm * 256 + wm * 64 + i * 16 + quad * 4;
            #pragma unroll
            for (int r = 0; r < 4; ++r)
                out[(size_t)(mbase + r) * DMODEL + n] = acc[i][j][r] + bov;
        }
    }
}

// ---------------------------------------------------------------------------
extern "C" void kernel_launch(void* const* d_in, const int* in_sizes, int n_in,
                              void* d_out, int out_size, void* d_ws, size_t ws_size,
                              hipStream_t stream)
{
    const float* xs = (const float*)d_in[0];
    const float* Wz = (const float*)d_in[1];
    const float* bz = (const float*)d_in[2];
    const float* Wh = (const float*)d_in[3];
    const float* bh = (const float*)d_in[4];
    const float* Wo = (const float*)d_in[5];
    const float* bo = (const float*)d_in[6];
    float* out = (float*)d_out;

    char* w = (char*)d_ws;
    unsigned int*   ab_ws  = (unsigned int*)  (w);               // 33,554,432
    unsigned short* states = (unsigned short*)(w + 33554432ull); // 16,777,216
    bf16*  Wz_c   = (bf16*) (w + 50331648ull);                   //    524,288
    bf16*  Wh_c   = (bf16*) (w + 50855936ull);                   //    524,288
    bf16*  Wo_c   = (bf16*) (w + 51380224ull);                   //    524,288
    float* ABagg  = (float*)(w + 51904512ull);                   //  2,097,152
    float* HpreT  = (float*)(w + 54001664ull);                   //  1,048,576

    k_convert<<<(N4_W3 + 255) / 256, 256, 0, stream>>>(Wz, Wh, Wo, Wz_c, Wh_c, Wo_c);
    gemm_zh<<<dim3(64, 4), 512, 0, stream>>>(xs, Wz_c, bz, Wh_c, bh, ab_ws, ABagg);
    scan_p2<<<DMODEL, NCHUNK, 0, stream>>>(ABagg, HpreT);
    scan_p3<<<dim3(NCHUNK, 2), 256, 0, stream>>>(ab_ws, HpreT, states);
    gemm_out<<<dim3(64, 4), 512, 0, stream>>>((const bf16*)states, Wo_c, bo, out);
}

// Round 9
// 147.612 us; speedup vs baseline: 1.0487x; 1.0487x over previous
//
#include <hip/hip_runtime.h>
#include <hip/hip_bf16.h>
#include <cstdint>
#include <cmath>

// Problem constants — inputs/outputs are fp32.
// LEDGER: R0 152.3 | R1 167.4 | R2 151.8 | R3 150.2 | R4 152.3 | R5 172.9 |
//         R6 153.3 | R7 148.8 (BEST) | R8 154.8 (fp32-A staging: swizzle
//         broken for 128B rows -> 1.05M bank conflicts + 1blk/CU; reverted).
// LESSON (R7): row-major LDS = 16-way conflict; XOR slot swizzle -> 0 — but
// the swizzle family is row-period-dependent: works for 64B bf16 rows,
// NOT for 128B fp32 rows (R8: conflicts 0 -> 2^20).
// LESSON (R8): __syncthreads() drains vmcnt(0)/K-step; raw s_barrier + counted
// vmcnt in K-loops.
// LESSON (R10/R11): rocprof per-kernel dur unreliable under replay; trust
// bench totals only.
// LESSON (R12): reg-staging commit (ds_write+lgkmcnt per phase) regressed;
// DMA staging strictly better; k_convert pays for itself.
// LESSON (R13): p3+out fusion lost (1 blk/CU serial scan uncovered); keep split.
// LESSON (R14): write-allocate on scattered 8B stores is real (~1.4us);
// interleaved float4 agg store fixed it (R7's win).
// R9: R7 restored byte-for-byte. This is the terminal configuration; the
// remaining total is harness fills (~42us @ 80% HBM) + five memory-floor
// kernels + launch gaps — structural, not schedule-addressable.
#define T_SEQ 16384
#define DMODEL 512
#define NCHUNK 512        // scan chunks (= T_SEQ/LCHUNK)
#define LCHUNK 32
#define W_N    (DMODEL * DMODEL)
#define N4_W   (W_N / 4)
#define N4_W3  (3 * N4_W)
#define N4_X   (T_SEQ * DMODEL / 4)
#define N4_ALL (N4_W3 + N4_X)
#define NTILE  8          // K tiles of 64

typedef __bf16 bf16x8 __attribute__((ext_vector_type(8)));
typedef float  f32x4  __attribute__((ext_vector_type(4)));

using bf16 = __hip_bfloat16;

__device__ __forceinline__ void load_lds16(const void* g, void* l) {
    __builtin_amdgcn_global_load_lds((const __attribute__((address_space(1))) void*)g,
                                     (__attribute__((address_space(3))) void*)l,
                                     16, 0, 0);
}

__device__ __forceinline__ unsigned short f2bf(float f) {
    union { float f; unsigned u; } v; v.f = f;
    const unsigned r = (v.u + 0x7FFFu + ((v.u >> 16) & 1u)) >> 16;
    return (unsigned short)r;
}
__device__ __forceinline__ float bf2f(unsigned short u) {
    union { unsigned u; float f; } v; v.u = ((unsigned)u) << 16;
    return v.f;
}

// ordered pair-combine: first=(fA,fB) then second=(sA,sB)
__device__ __forceinline__ void comb(float& A, float& B, float fA, float fB,
                                     float sA, float sB) {
    A = fA * sA;
    B = sA * fB + sB;
}

// ---------------------------------------------------------------------------
// Kernel 0: convert Wz, Wh, Wo AND xs fp32 -> bf16 (~52 MB, ~9 us).
// ---------------------------------------------------------------------------
__global__ __launch_bounds__(256) void k_convert(
    const float* __restrict__ xs,
    const float* __restrict__ Wz, const float* __restrict__ Wh,
    const float* __restrict__ Wo,
    bf16* __restrict__ xs_c, bf16* __restrict__ Wz_c,
    bf16* __restrict__ Wh_c, bf16* __restrict__ Wo_c)
{
    const int i = blockIdx.x * 256 + threadIdx.x;
    if (i >= N4_ALL) return;
    const float* src; bf16* dst; int o;
    if (i < N4_W3) {
        const int w = i >> 16; o = i & 65535;
        src = (w == 0) ? Wz : (w == 1) ? Wh : Wo;
        dst = (w == 0) ? Wz_c : (w == 1) ? Wh_c : Wo_c;
    } else {
        o = i - N4_W3; src = xs; dst = xs_c;
    }
    const float4 v = ((const float4*)src)[o];
    ushort4 r;
    r.x = f2bf(v.x); r.y = f2bf(v.y); r.z = f2bf(v.z); r.w = f2bf(v.w);
    ((ushort4*)dst)[o] = r;
}

// ---------------------------------------------------------------------------
// Kernel 1: fused dual GEMM + scan phase 1 — R3-best 256x128 4-phase template.
// Agg epilogue stores one float4 {Alo,Blo,Ahi,Bhi} into interleaved ABagg
// (16B/lane, no write-allocate waste).
// ---------------------------------------------------------------------------
__global__ __launch_bounds__(512, 2) void gemm_zh(
    const bf16* __restrict__ xs_c, const bf16* __restrict__ Wz, const float* __restrict__ bz,
    const bf16* __restrict__ Wh, const float* __restrict__ bh,
    unsigned int* __restrict__ ab_ws,
    float* __restrict__ ABagg)
{
    __shared__ __bf16 As[2][2][256 * 32];   // 64 KB
    __shared__ __bf16 Zs[2][2][128 * 32];   // 32 KB
    __shared__ __bf16 Hs[2][2][128 * 32];   // 32 KB

    const int tid  = threadIdx.x;
    const int bm   = blockIdx.x;   // 0..63  (M tile of 256)
    const int bn   = blockIdx.y;   // 0..3   (N tile of 128)
    const int lane = tid & 63;
    const int wave = tid >> 6;     // 0..7
    const int wm   = wave >> 1;    // 0..3
    const int wn   = wave & 1;     // 0..1
    const int quad = lane >> 4;
    const int col  = lane & 15;

    f32x4 accz[4][4], acch[4][4];
    #pragma unroll
    for (int i = 0; i < 4; ++i)
        #pragma unroll
        for (int j = 0; j < 4; ++j) {
            accz[i][j] = (f32x4){0.f, 0.f, 0.f, 0.f};
            acch[i][j] = (f32x4){0.f, 0.f, 0.f, 0.f};
        }

    // staging: linear LDS dest, pre-swizzled global source.
    const int srow = tid >> 2;                        // 0..127
    const int wq   = (tid & 3) ^ ((tid >> 3) & 3);
    const bf16* ag = xs_c + (size_t)(bm * 256 + srow) * DMODEL + wq * 8;
    const bf16* zg = Wz   + (size_t)(bn * 128 + srow) * DMODEL + wq * 8;
    const bf16* hg = Wh   + (size_t)(bn * 128 + srow) * DMODEL + wq * 8;

    // fragment read offsets (swizzled slot fq within 32-elem rows)
    const int fq = quad ^ ((col >> 1) & 3);
    int offA[4], offB[4];
    #pragma unroll
    for (int i = 0; i < 4; ++i) {
        offA[i] = (wm * 64 + i * 16 + col) * 32 + fq * 8;
        offB[i] = (wn * 64 + i * 16 + col) * 32 + fq * 8;
    }

    // 4 loads per half-tile per thread (A x2, Z, H)
    auto STAGE_HALF = [&](int t, int h) {
        const int b  = t & 1;
        const int ko = t * 64 + h * 32;
        load_lds16(ag + ko,                          &As[b][h][tid * 8]);
        load_lds16(ag + (size_t)128 * DMODEL + ko,   &As[b][h][(512 + tid) * 8]);
        load_lds16(zg + ko,                          &Zs[b][h][tid * 8]);
        load_lds16(hg + ko,                          &Hs[b][h][tid * 8]);
    };

    // prologue: tile 0 fully in flight (8 loads/thread)
    STAGE_HALF(0, 0); STAGE_HALF(0, 1);

    #pragma unroll
    for (int t = 0; t < NTILE; ++t) {
        const int b = t & 1;
        bf16x8 af[4], zf[4], hf[4];

        // ---- Phase A: Z-gemm, half 0 (fresh) ----
        asm volatile("s_waitcnt vmcnt(4)" ::: "memory");
        __builtin_amdgcn_s_barrier();
        __builtin_amdgcn_sched_barrier(0);
        if (t + 1 < NTILE) STAGE_HALF(t + 1, 0);
        #pragma unroll
        for (int i = 0; i < 4; ++i) {
            af[i] = *(const bf16x8*)&As[b][0][offA[i]];
            zf[i] = *(const bf16x8*)&Zs[b][0][offB[i]];
        }
        __builtin_amdgcn_s_setprio(1);
        #pragma unroll
        for (int i = 0; i < 4; ++i)
            #pragma unroll
            for (int j = 0; j < 4; ++j)
                accz[i][j] = __builtin_amdgcn_mfma_f32_16x16x32_bf16(af[i], zf[j], accz[i][j], 0, 0, 0);
        __builtin_amdgcn_s_setprio(0);

        // ---- Phase B: H-gemm, half 0 (af reused in regs) ----
        #pragma unroll
        for (int j = 0; j < 4; ++j)
            hf[j] = *(const bf16x8*)&Hs[b][0][offB[j]];
        __builtin_amdgcn_s_setprio(1);
        #pragma unroll
        for (int i = 0; i < 4; ++i)
            #pragma unroll
            for (int j = 0; j < 4; ++j)
                acch[i][j] = __builtin_amdgcn_mfma_f32_16x16x32_bf16(af[i], hf[j], acch[i][j], 0, 0, 0);
        __builtin_amdgcn_s_setprio(0);

        // ---- Phase C: Z-gemm, half 1 (fresh) ----
        if (t + 1 < NTILE) {
            asm volatile("s_waitcnt vmcnt(4)" ::: "memory");
        } else {
            asm volatile("s_waitcnt vmcnt(0)" ::: "memory");
        }
        __builtin_amdgcn_s_barrier();
        __builtin_amdgcn_sched_barrier(0);
        if (t + 1 < NTILE) STAGE_HALF(t + 1, 1);
        #pragma unroll
        for (int i = 0; i < 4; ++i) {
            af[i] = *(const bf16x8*)&As[b][1][offA[i]];
            zf[i] = *(const bf16x8*)&Zs[b][1][offB[i]];
        }
        __builtin_amdgcn_s_setprio(1);
        #pragma unroll
        for (int i = 0; i < 4; ++i)
            #pragma unroll
            for (int j = 0; j < 4; ++j)
                accz[i][j] = __builtin_amdgcn_mfma_f32_16x16x32_bf16(af[i], zf[j], accz[i][j], 0, 0, 0);
        __builtin_amdgcn_s_setprio(0);

        // ---- Phase D: H-gemm, half 1 ----
        #pragma unroll
        for (int j = 0; j < 4; ++j)
            hf[j] = *(const bf16x8*)&Hs[b][1][offB[j]];
        __builtin_amdgcn_s_setprio(1);
        #pragma unroll
        for (int i = 0; i < 4; ++i)
            #pragma unroll
            for (int j = 0; j < 4; ++j)
                acch[i][j] = __builtin_amdgcn_mfma_f32_16x16x32_bf16(af[i], hf[j], acch[i][j], 0, 0, 0);
        __builtin_amdgcn_s_setprio(0);
    }

    // epilogue: D layout col=lane&15 (n), row=quad*4+reg (m)
    const int c_lo = bm * 8 + wm * 2;      // 8 chunks per 256-row tile
    #pragma unroll
    for (int j = 0; j < 4; ++j) {
        const int n = bn * 128 + wn * 64 + j * 16 + col;
        const float bzv = bz[n];
        const float bhv = bh[n];
        float cA[4], cB[4];
        #pragma unroll
        for (int i = 0; i < 4; ++i) {
            const int mbase = bm * 256 + wm * 64 + i * 16 + quad * 4;
            float A = 1.f, B = 0.f;
            #pragma unroll
            for (int r = 0; r < 4; ++r) {
                const float zpre = accz[i][j][r] + bzv;
                const float hpre = acch[i][j][r] + bhv;
                const float z = 1.f / (1.f + __expf(-zpre));
                const float a = 1.f - z;
                const float b = z * hpre;
                const size_t idx = (size_t)(mbase + r) * DMODEL + n;
                ab_ws[idx] = (unsigned)f2bf(a) | ((unsigned)f2bf(b) << 16);
                A = a * A;
                B = a * B + b;
            }
            cA[i] = A; cB[i] = B;
        }
        #pragma unroll
        for (int i = 0; i < 4; ++i) {
            float pA = __shfl_xor(cA[i], 16);
            float pB = __shfl_xor(cB[i], 16);
            const bool hi1 = quad & 1;
            comb(cA[i], cB[i], hi1 ? pA : cA[i], hi1 ? pB : cB[i],
                               hi1 ? cA[i] : pA, hi1 ? cB[i] : pB);
            pA = __shfl_xor(cA[i], 32);
            pB = __shfl_xor(cB[i], 32);
            const bool hi2 = quad >> 1;
            comb(cA[i], cB[i], hi2 ? pA : cA[i], hi2 ? pB : cB[i],
                               hi2 ? cA[i] : pA, hi2 ? cB[i] : pB);
        }
        float Alo, Blo, Ahi, Bhi;
        comb(Alo, Blo, cA[0], cB[0], cA[1], cB[1]);
        comb(Ahi, Bhi, cA[2], cB[2], cA[3], cB[3]);
        if (quad == 0) {   // interleaved {A,B} pairs: one 16B store per lane
            *(float4*)&ABagg[((size_t)n * NCHUNK + c_lo) * 2] =
                make_float4(Alo, Blo, Ahi, Bhi);
        }
    }
}

// ---------------------------------------------------------------------------
// Kernel 2: per-channel Hillis-Steele over NCHUNK chunk aggregates.
// Reads interleaved ABagg as coalesced float2.
// ---------------------------------------------------------------------------
__global__ __launch_bounds__(512) void scan_p2(
    const float* __restrict__ ABagg, float* __restrict__ HpreT)
{
    const int h = blockIdx.x;
    const int c = threadIdx.x;
    __shared__ float sA[NCHUNK], sB[NCHUNK];

    const float2 v = ((const float2*)ABagg)[(size_t)h * NCHUNK + c];
    float A = v.x;
    float B = v.y;
    sA[c] = A; sB[c] = B;
    __syncthreads();

    for (int off = 1; off < NCHUNK; off <<= 1) {
        float pA = 1.f, pB = 0.f;
        if (c >= off) { pA = sA[c - off]; pB = sB[c - off]; }
        __syncthreads();
        const float nB = A * pB + B;   // uses old A
        const float nA = A * pA;
        A = nA; B = nB;
        sA[c] = A; sB[c] = B;
        __syncthreads();
    }
    const float hp = (c == 0) ? 0.f : sB[c - 1];
    HpreT[(size_t)h * NCHUNK + c] = hp;
}

// ---------------------------------------------------------------------------
// Kernel 3: replay chunk recurrence from HpreT; write bf16 states.
// 1 channel/thread, grid (512 chunks x 2 halves) x 256 threads -> 4 blk/CU.
// NOTE: writes 'states' which aliases xs_c — safe, gemm_zh done by now.
// ---------------------------------------------------------------------------
__global__ __launch_bounds__(256) void scan_p3(
    const unsigned int* __restrict__ ab_ws, const float* __restrict__ HpreT,
    unsigned short* __restrict__ states)
{
    const int tid = threadIdx.x;
    const int c   = blockIdx.x;
    const int ch  = blockIdx.y * 256 + tid;
    float H = HpreT[(size_t)ch * NCHUNK + c];       // one-time gather
    const size_t base = (size_t)(c * LCHUNK) * DMODEL + ch;
    #pragma unroll 8
    for (int i = 0; i < LCHUNK; ++i) {
        const unsigned u = ab_ws[base + (size_t)i * DMODEL];
        const float a = bf2f((unsigned short)(u & 0xFFFFu));
        const float b = bf2f((unsigned short)(u >> 16));
        H = a * H + b;
        states[base + (size_t)i * DMODEL] = f2bf(H);
    }
}

// ---------------------------------------------------------------------------
// Kernel 4: out = states @ Wo^T + bo — R3-proven 256x128 template.
// 512 thr / 8 waves, BK=64 as 2x32 halves, 96 KB LDS, counted vmcnt(3),
// setprio around MFMA clusters.
// ---------------------------------------------------------------------------
__global__ __launch_bounds__(512, 2) void gemm_out(
    const bf16* __restrict__ states, const bf16* __restrict__ Wo, const float* __restrict__ bo,
    float* __restrict__ out)
{
    __shared__ __bf16 As[2][2][256 * 32];   // 64 KB
    __shared__ __bf16 Bs[2][2][128 * 32];   // 32 KB

    const int tid  = threadIdx.x;
    const int bm   = blockIdx.x;   // 0..63
    const int bn   = blockIdx.y;   // 0..3
    const int lane = tid & 63;
    const int wave = tid >> 6;
    const int wm   = wave >> 1;    // 0..3
    const int wn   = wave & 1;     // 0..1
    const int quad = lane >> 4;
    const int col  = lane & 15;

    f32x4 acc[4][4];
    #pragma unroll
    for (int i = 0; i < 4; ++i)
        #pragma unroll
        for (int j = 0; j < 4; ++j)
            acc[i][j] = (f32x4){0.f, 0.f, 0.f, 0.f};

    const int srow = tid >> 2;
    const int wq   = (tid & 3) ^ ((tid >> 3) & 3);
    const bf16* ag = states + (size_t)(bm * 256 + srow) * DMODEL + wq * 8;
    const bf16* bg = Wo     + (size_t)(bn * 128 + srow) * DMODEL + wq * 8;

    const int fq = quad ^ ((col >> 1) & 3);
    int offA[4], offB[4];
    #pragma unroll
    for (int i = 0; i < 4; ++i) {
        offA[i] = (wm * 64 + i * 16 + col) * 32 + fq * 8;
        offB[i] = (wn * 64 + i * 16 + col) * 32 + fq * 8;
    }

    auto STAGE_HALF = [&](int t, int h) {
        const int b  = t & 1;
        const int ko = t * 64 + h * 32;
        load_lds16(ag + ko,                        &As[b][h][tid * 8]);
        load_lds16(ag + (size_t)128 * DMODEL + ko, &As[b][h][(512 + tid) * 8]);
        load_lds16(bg + ko,                        &Bs[b][h][tid * 8]);
    };

    STAGE_HALF(0, 0); STAGE_HALF(0, 1);

    #pragma unroll
    for (int t = 0; t < NTILE; ++t) {
        const int b = t & 1;
        bf16x8 af[4], bf[4];

        // ---- Phase 0: k-half 0 (fresh) ----
        asm volatile("s_waitcnt vmcnt(3)" ::: "memory");
        __builtin_amdgcn_s_barrier();
        __builtin_amdgcn_sched_barrier(0);
        if (t + 1 < NTILE) STAGE_HALF(t + 1, 0);
        #pragma unroll
        for (int i = 0; i < 4; ++i) {
            af[i] = *(const bf16x8*)&As[b][0][offA[i]];
            bf[i] = *(const bf16x8*)&Bs[b][0][offB[i]];
        }
        __builtin_amdgcn_s_setprio(1);
        #pragma unroll
        for (int i = 0; i < 4; ++i)
            #pragma unroll
            for (int j = 0; j < 4; ++j)
                acc[i][j] = __builtin_amdgcn_mfma_f32_16x16x32_bf16(af[i], bf[j], acc[i][j], 0, 0, 0);
        __builtin_amdgcn_s_setprio(0);

        // ---- Phase 1: k-half 1 (fresh) ----
        if (t + 1 < NTILE) {
            asm volatile("s_waitcnt vmcnt(3)" ::: "memory");
        } else {
            asm volatile("s_waitcnt vmcnt(0)" ::: "memory");
        }
        __builtin_amdgcn_s_barrier();
        __builtin_amdgcn_sched_barrier(0);
        if (t + 1 < NTILE) STAGE_HALF(t + 1, 1);
        #pragma unroll
        for (int i = 0; i < 4; ++i) {
            af[i] = *(const bf16x8*)&As[b][1][offA[i]];
            bf[i] = *(const bf16x8*)&Bs[b][1][offB[i]];
        }
        __builtin_amdgcn_s_setprio(1);
        #pragma unroll
        for (int i = 0; i < 4; ++i)
            #pragma unroll
            for (int j = 0; j < 4; ++j)
                acc[i][j] = __builtin_amdgcn_mfma_f32_16x16x32_bf16(af[i], bf[j], acc[i][j], 0, 0, 0);
        __builtin_amdgcn_s_setprio(0);
    }

    #pragma unroll
    for (int j = 0; j < 4; ++j) {
        const int n = bn * 128 + wn * 64 + j * 16 + col;
        const float bov = bo[n];
        #pragma unroll
        for (int i = 0; i < 4; ++i) {
            const int mbase = bm * 256 + wm * 64 + i * 16 + quad * 4;
            #pragma unroll
            for (int r = 0; r < 4; ++r)
                out[(size_t)(mbase + r) * DMODEL + n] = acc[i][j][r] + bov;
        }
    }
}

// ---------------------------------------------------------------------------
extern "C" void kernel_launch(void* const* d_in, const int* in_sizes, int n_in,
                              void* d_out, int out_size, void* d_ws, size_t ws_size,
                              hipStream_t stream)
{
    const float* xs = (const float*)d_in[0];
    const float* Wz = (const float*)d_in[1];
    const float* bz = (const float*)d_in[2];
    const float* Wh = (const float*)d_in[3];
    const float* bh = (const float*)d_in[4];
    const float* Wo = (const float*)d_in[5];
    const float* bo = (const float*)d_in[6];
    float* out = (float*)d_out;

    char* w = (char*)d_ws;
    unsigned int* ab_ws = (unsigned int*)(w);            // 33,554,432
    bf16*  xs_c   = (bf16*) (w + 33554432ull);           // 16,777,216
    bf16*  Wz_c   = (bf16*) (w + 50331648ull);           //    524,288
    bf16*  Wh_c   = (bf16*) (w + 50855936ull);           //    524,288
    bf16*  Wo_c   = (bf16*) (w + 51380224ull);           //    524,288
    float* ABagg  = (float*)(w + 51904512ull);           //  2,097,152
    float* HpreT  = (float*)(w + 54001664ull);           //  1,048,576
    // states aliases xs_c: xs_c dead after gemm_zh; states born in scan_p3.
    unsigned short* states = (unsigned short*)xs_c;

    k_convert<<<(N4_ALL + 255) / 256, 256, 0, stream>>>(xs, Wz, Wh, Wo, xs_c, Wz_c, Wh_c, Wo_c);
    gemm_zh<<<dim3(64, 4), 512, 0, stream>>>(xs_c, Wz_c, bz, Wh_c, bh, ab_ws, ABagg);
    scan_p2<<<DMODEL, NCHUNK, 0, stream>>>(ABagg, HpreT);
    scan_p3<<<dim3(NCHUNK, 2), 256, 0, stream>>>(ab_ws, HpreT, states);
    gemm_out<<<dim3(64, 4), 512, 0, stream>>>((const bf16*)states, Wo_c, bo, out);
}